// Round 1
// baseline (67.290 us; speedup 1.0000x reference)
//
#include <hip/hip_runtime.h>
#include <stdint.h>
#include <stddef.h>

#define NB 8
#define SS 512
#define HID 1024
#define NHEADS 12
#define HSZ 64
#define NPROJ 1536
#define MROWS 4096
#define NEG_INF 1000000000000.0f

typedef __attribute__((ext_vector_type(4))) float f32x4;
typedef __attribute__((ext_vector_type(8))) __bf16 bf16x8;
typedef __attribute__((ext_vector_type(4))) unsigned short us4;

typedef __attribute__((address_space(1))) unsigned char gu8;
typedef __attribute__((address_space(3))) unsigned char lu8;

static __device__ __forceinline__ void gld16(const void* g, void* l) {
  __builtin_amdgcn_global_load_lds((gu8*)(g), (lu8*)(l), 16, 0, 0);
}

static __device__ __forceinline__ unsigned short f2bf(float f) {
  union { float f; unsigned u; } x; x.f = f;
  unsigned r = x.u + 0x7fffu + ((x.u >> 16) & 1u);
  return (unsigned short)(r >> 16);
}

// ---- sincos table: tab[s*32+i] = (sin(s*rate_i), cos(s*rate_i)), rate_i = 10000^(-i/32)
__global__ void k_table(float2* __restrict__ tab) {
  int t = blockIdx.x * 256 + threadIdx.x;  // 16384 total
  int s = t >> 5, i = t & 31;
  float rate = powf(10000.0f, -(float)i / 32.0f);
  float ang = (float)s * rate;
  float sv, cv;
  sincosf(ang, &sv, &cv);
  tab[t] = make_float2(sv, cv);
}

// ---- x f32 -> bf16 (4 elems/thread)
__global__ void k_cvtx(const float4* __restrict__ x, us4* __restrict__ xb) {
  int i = blockIdx.x * 256 + threadIdx.x;  // 1048576 total
  float4 v = x[i];
  us4 o;
  o[0] = f2bf(v.x); o[1] = f2bf(v.y); o[2] = f2bf(v.z); o[3] = f2bf(v.w);
  xb[i] = o;
}

// ---- W (1024 x 1536 f32, k-major rows) -> WbT (1536 x 1024 bf16)
__global__ void k_wt(const float* __restrict__ W, unsigned short* __restrict__ wbt) {
  __shared__ float t[32][33];
  int tx = threadIdx.x & 31, ty = threadIdx.x >> 5;  // 32x8
  int n0 = blockIdx.x * 32, k0 = blockIdx.y * 32;
#pragma unroll
  for (int i = 0; i < 4; ++i)
    t[ty + i * 8][tx] = W[(k0 + ty + i * 8) * NPROJ + n0 + tx];
  __syncthreads();
#pragma unroll
  for (int i = 0; i < 4; ++i)
    wbt[(n0 + ty + i * 8) * HID + (k0 + tx)] = f2bf(t[tx][ty + i * 8]);
}

// ---- GEMM1: proj = xb(4096x1024) * WbT(1536x1024)^T, fused bias + RoPE -> q,k bf16
// LDS tiles [128 rows][64 k] bf16, XOR-swizzled: byte (row,cb) holds data (row, cb^((row&7)<<4))
__global__ __launch_bounds__(256) void k_proj(
    const unsigned short* __restrict__ xb, const unsigned short* __restrict__ wbt,
    const float* __restrict__ bias, const float2* __restrict__ tab,
    unsigned short* __restrict__ qo, unsigned short* __restrict__ ko) {
  __shared__ __align__(16) unsigned short lA[128 * 64];
  __shared__ __align__(16) unsigned short lB[128 * 64];
  const int tid = threadIdx.x;
  const int lane = tid & 63, w = tid >> 6;
  const int wm = w >> 1, wn = w & 1;
  const int m0 = blockIdx.x * 128, n0 = blockIdx.y * 128;

  f32x4 acc[4][4];
#pragma unroll
  for (int a = 0; a < 4; ++a)
#pragma unroll
    for (int bb = 0; bb < 4; ++bb)
      acc[a][bb] = (f32x4)(0.0f);

  // staging geometry: wave w stages chunks w*4..w*4+3 (1 KB each) of each tile
  int srow[4], soff[4];
#pragma unroll
  for (int c = 0; c < 4; ++c) {
    int lin = (w * 4 + c) * 1024 + lane * 16;
    int row = lin >> 7;
    int cb = lin & 127;
    srow[c] = row;
    soff[c] = cb ^ ((row & 7) << 4);  // pre-swizzled source, linear LDS dest
  }

  for (int kt = 0; kt < HID / 64; ++kt) {
#pragma unroll
    for (int c = 0; c < 4; ++c) {
      int chunk = w * 4 + c;
      gld16((const char*)(xb + (m0 + srow[c]) * HID + kt * 64) + soff[c],
            (char*)lA + chunk * 1024);
      gld16((const char*)(wbt + (n0 + srow[c]) * HID + kt * 64) + soff[c],
            (char*)lB + chunk * 1024);
    }
    __syncthreads();
#pragma unroll
    for (int ks = 0; ks < 2; ++ks) {
      bf16x8 af[4], bfr[4];
      const int kb = ks * 64 + (lane >> 4) * 16;
#pragma unroll
      for (int mi = 0; mi < 4; ++mi) {
        int row = wm * 64 + mi * 16 + (lane & 15);
        af[mi] = *(const bf16x8*)((const char*)lA + row * 128 + (kb ^ ((row & 7) << 4)));
      }
#pragma unroll
      for (int ni = 0; ni < 4; ++ni) {
        int row = wn * 64 + ni * 16 + (lane & 15);
        bfr[ni] = *(const bf16x8*)((const char*)lB + row * 128 + (kb ^ ((row & 7) << 4)));
      }
#pragma unroll
      for (int mi = 0; mi < 4; ++mi)
#pragma unroll
        for (int ni = 0; ni < 4; ++ni)
          acc[mi][ni] = __builtin_amdgcn_mfma_f32_16x16x32_bf16(af[mi], bfr[ni], acc[mi][ni], 0, 0, 0);
    }
    __syncthreads();
  }

  // epilogue: + bias, RoPE (pair col^1 lives in lane^1), scatter bf16 to q/k [b][h][s][d]
#pragma unroll
  for (int mi = 0; mi < 4; ++mi) {
#pragma unroll
    for (int ni = 0; ni < 4; ++ni) {
      const int col = n0 + wn * 64 + ni * 16 + (lane & 15);
      const float bv = bias[col];
      const int d = col & 63;           // head dim index
      const int h = col >> 7;           // head
      const int j = col & 127;          // j<64 -> q, else k (wave-uniform: depends on wn only)
      unsigned short* dst = (j < HSZ) ? qo : ko;
      const float sgn = (d & 1) ? 1.0f : -1.0f;
#pragma unroll
      for (int r = 0; r < 4; ++r) {
        const int row = m0 + wm * 64 + mi * 16 + (lane >> 4) * 4 + r;
        const int s = row & (SS - 1);
        const int bidx = row >> 9;
        float v = acc[mi][ni][r] + bv;
        float p = __shfl_xor(v, 1, 64);  // value at col^1 (same row, same reg)
        float2 sc = tab[s * 32 + (d & 31)];
        float o = v * sc.y + sgn * p * sc.x;
        dst[((bidx * NHEADS + h) * SS + s) * HSZ + d] = f2bf(o);
      }
    }
  }
}

// ---- GEMM2: logits[b,h,m,n] = dot(q[bh][m], k[bh][n]) with mask/causal/scale
__global__ __launch_bounds__(256) void k_logits(
    const unsigned short* __restrict__ q, const unsigned short* __restrict__ kk,
    const float* __restrict__ mask, float* __restrict__ out) {
  __shared__ __align__(16) unsigned short lQ[128 * 64];
  __shared__ __align__(16) unsigned short lK[128 * 64];
  const int tid = threadIdx.x;
  const int lane = tid & 63, w = tid >> 6;
  const int wm = w >> 1, wn = w & 1;
  const int bh = blockIdx.y;
  const int b = bh / NHEADS;
  const int m0 = (blockIdx.x >> 2) * 128, n0 = (blockIdx.x & 3) * 128;
  const char* qbase = (const char*)(q + (size_t)bh * SS * HSZ) + m0 * 128;
  const char* kbase = (const char*)(kk + (size_t)bh * SS * HSZ) + n0 * 128;

#pragma unroll
  for (int c = 0; c < 4; ++c) {
    int chunk = w * 4 + c;
    int lin = chunk * 1024 + lane * 16;
    int row = lin >> 7, cb = lin & 127;
    int sw = cb ^ ((row & 7) << 4);
    gld16(qbase + row * 128 + sw, (char*)lQ + chunk * 1024);
    gld16(kbase + row * 128 + sw, (char*)lK + chunk * 1024);
  }
  __syncthreads();

  f32x4 acc[4][4];
#pragma unroll
  for (int a = 0; a < 4; ++a)
#pragma unroll
    for (int bb = 0; bb < 4; ++bb)
      acc[a][bb] = (f32x4)(0.0f);

#pragma unroll
  for (int ks = 0; ks < 2; ++ks) {
    bf16x8 af[4], bfr[4];
    const int kb = ks * 64 + (lane >> 4) * 16;
#pragma unroll
    for (int mi = 0; mi < 4; ++mi) {
      int row = wm * 64 + mi * 16 + (lane & 15);
      af[mi] = *(const bf16x8*)((const char*)lQ + row * 128 + (kb ^ ((row & 7) << 4)));
    }
#pragma unroll
    for (int ni = 0; ni < 4; ++ni) {
      int row = wn * 64 + ni * 16 + (lane & 15);
      bfr[ni] = *(const bf16x8*)((const char*)lK + row * 128 + (kb ^ ((row & 7) << 4)));
    }
#pragma unroll
    for (int mi = 0; mi < 4; ++mi)
#pragma unroll
      for (int ni = 0; ni < 4; ++ni)
        acc[mi][ni] = __builtin_amdgcn_mfma_f32_16x16x32_bf16(af[mi], bfr[ni], acc[mi][ni], 0, 0, 0);
  }

  // epilogue: mask (exact arithmetic form of reference), causal, /8
  float mc[4];
#pragma unroll
  for (int ni = 0; ni < 4; ++ni)
    mc[ni] = mask[b * SS + n0 + wn * 64 + ni * 16 + (lane & 15)];
#pragma unroll
  for (int mi = 0; mi < 4; ++mi) {
#pragma unroll
    for (int r = 0; r < 4; ++r) {
      const int m = m0 + wm * 64 + mi * 16 + (lane >> 4) * 4 + r;
      const float mr = mask[b * SS + m];
#pragma unroll
      for (int ni = 0; ni < 4; ++ni) {
        const int n = n0 + wn * 64 + ni * 16 + (lane & 15);
        float v = acc[mi][ni][r];
        v = v * mr - NEG_INF * (1.0f - mr);
        v = v * mc[ni] - NEG_INF * (1.0f - mc[ni]);
        if (m > n) v -= NEG_INF;
        v *= 0.125f;
        out[((size_t)bh * SS + m) * SS + n] = v;
      }
    }
  }
}

extern "C" void kernel_launch(void* const* d_in, const int* in_sizes, int n_in,
                              void* d_out, int out_size, void* d_ws, size_t ws_size,
                              hipStream_t stream) {
  const float* x = (const float*)d_in[0];
  const float* mask = (const float*)d_in[1];
  const float* W = (const float*)d_in[2];
  const float* bias = (const float*)d_in[3];
  float* out = (float*)d_out;

  char* ws = (char*)d_ws;
  float2* tab = (float2*)ws;                                   // 131072 B
  unsigned short* xb = (unsigned short*)(ws + 131072);         // 8 MB
  unsigned short* wbt = (unsigned short*)(ws + 131072 + 8388608);          // 3 MB
  unsigned short* qo = (unsigned short*)(ws + 131072 + 8388608 + 3145728); // 6.29 MB
  unsigned short* ko = (unsigned short*)(ws + 131072 + 8388608 + 3145728 + 6291456);

  k_table<<<dim3(64), dim3(256), 0, stream>>>(tab);
  k_cvtx<<<dim3(4096), dim3(256), 0, stream>>>((const float4*)x, (us4*)xb);
  k_wt<<<dim3(48, 32), dim3(256), 0, stream>>>(W, wbt);
  k_proj<<<dim3(32, 12), dim3(256), 0, stream>>>(xb, wbt, bias, tab, qo, ko);
  k_logits<<<dim3(16, 96), dim3(256), 0, stream>>>(qo, ko, mask, out);
}